// Round 1
// baseline (864.001 us; speedup 1.0000x reference)
//
#include <hip/hip_runtime.h>

#define NN 100000
#define NE 600000

// ---------------- degree ----------------
__global__ void deg_kernel(const int* __restrict__ dst, int* __restrict__ deg) {
  int i = blockIdx.x * blockDim.x + threadIdx.x;
  int n = gridDim.x * blockDim.x;
  for (; i < NE; i += n) atomicAdd(&deg[dst[i]], 1);
}

__global__ void dinv_kernel(const int* __restrict__ deg, float* __restrict__ dinv) {
  int i = blockIdx.x * blockDim.x + threadIdx.x;
  if (i < NN) dinv[i] = rsqrtf((float)deg[i] + 1.0f);
}

// ---------------- GEMM: h = act(in) @ W ; agg = dinv^2 * h + b ----------------
// in: [NN][128] f32. W: [128][NOUT]. Tile: 32 rows x NOUT cols per 256-thread block.
template<int NOUT, bool RELU>
__global__ __launch_bounds__(256) void gemm_kernel(
    const float* __restrict__ in, const float* __restrict__ W,
    const float* __restrict__ bias, const float* __restrict__ dinv,
    float* __restrict__ h, float* __restrict__ agg)
{
  __shared__ float xs[32 * 132];   // row-major tile, pad 132 (conflict-free)
  const int t = threadIdx.x;
  const int row0 = blockIdx.x * 32;

  // stage 32x128 input tile (float4 loads, b128 LDS writes)
  const float4* in4 = (const float4*)in;
  #pragma unroll
  for (int q = 0; q < 4; ++q) {
    int f = t + q * 256;          // float4 id within tile
    int r = f >> 5;               // 0..31
    int c4 = f & 31;              // 0..31
    float4 v = in4[(size_t)(row0 + r) * 32 + c4];
    if (RELU) {
      v.x = fmaxf(v.x, 0.f); v.y = fmaxf(v.y, 0.f);
      v.z = fmaxf(v.z, 0.f); v.w = fmaxf(v.w, 0.f);
    }
    *(float4*)&xs[r * 132 + c4 * 4] = v;
  }
  __syncthreads();

  constexpr int TC  = NOUT / 4;        // float4 col-groups: 32 or 16
  constexpr int RPT = 32 * TC / 256;   // rows per thread: 4 or 2
  const int tc = t % TC;
  const int tr = t / TC;
  const float4* W4 = (const float4*)W;

  float4 acc[RPT];
  #pragma unroll
  for (int i = 0; i < RPT; ++i) acc[i] = make_float4(0.f, 0.f, 0.f, 0.f);

  #pragma unroll 4
  for (int k = 0; k < 128; ++k) {
    float4 wv = W4[k * TC + tc];       // global, L1/L2 resident
    #pragma unroll
    for (int i = 0; i < RPT; ++i) {
      float xv = xs[(tr * RPT + i) * 132 + k];
      acc[i].x = fmaf(xv, wv.x, acc[i].x);
      acc[i].y = fmaf(xv, wv.y, acc[i].y);
      acc[i].z = fmaf(xv, wv.z, acc[i].z);
      acc[i].w = fmaf(xv, wv.w, acc[i].w);
    }
  }

  float4 b4 = ((const float4*)bias)[tc];
  float4* h4   = (float4*)h;
  float4* agg4 = (float4*)agg;
  #pragma unroll
  for (int i = 0; i < RPT; ++i) {
    int row = row0 + tr * RPT + i;
    float di  = dinv[row];
    float di2 = di * di;
    float4 a = acc[i];
    h4[(size_t)row * TC + tc] = a;
    float4 g;
    g.x = fmaf(a.x, di2, b4.x);
    g.y = fmaf(a.y, di2, b4.y);
    g.z = fmaf(a.z, di2, b4.z);
    g.w = fmaf(a.w, di2, b4.w);
    agg4[(size_t)row * TC + tc] = g;
  }
}

// ---------------- edge scatter: agg[dst] += coef * h[src] ----------------
template<int NOUT>
__global__ __launch_bounds__(256) void scatter_kernel(
    const int* __restrict__ src, const int* __restrict__ dst,
    const float* __restrict__ dinv, const float* __restrict__ h,
    float* __restrict__ agg)
{
  const int lane = threadIdx.x & 63;
  int w = (blockIdx.x * blockDim.x + threadIdx.x) >> 6;
  const int nw = (gridDim.x * blockDim.x) >> 6;
  for (int e = w; e < NE; e += nw) {
    int s = src[e], d = dst[e];
    float c = dinv[s] * dinv[d];
    if constexpr (NOUT == 128) {
      atomicAdd(&agg[(size_t)d * 128 + lane],      h[(size_t)s * 128 + lane] * c);
      atomicAdd(&agg[(size_t)d * 128 + lane + 64], h[(size_t)s * 128 + lane + 64] * c);
    } else {
      atomicAdd(&agg[(size_t)d * 64 + lane], h[(size_t)s * 64 + lane] * c);
    }
  }
}

extern "C" void kernel_launch(void* const* d_in, const int* in_sizes, int n_in,
                              void* d_out, int out_size, void* d_ws, size_t ws_size,
                              hipStream_t stream) {
  const float* x  = (const float*)d_in[0];
  const int*   ei = (const int*)d_in[1];
  const float* W1 = (const float*)d_in[2];
  const float* b1 = (const float*)d_in[3];
  const float* W2 = (const float*)d_in[4];
  const float* b2 = (const float*)d_in[5];
  const float* W3 = (const float*)d_in[6];
  const float* b3 = (const float*)d_in[7];
  float* out = (float*)d_out;

  const int* src = ei;
  const int* dst = ei + NE;

  float* ws   = (float*)d_ws;
  float* dinv = ws;                       // NN f32
  int*   deg  = (int*)(ws + NN);          // NN i32
  float* hA   = ws + 200000;              // NN*128
  float* aggA = hA + 12800000;            // NN*128
  float* hB   = aggA + 12800000;          // NN*128
  float* aggB = hB + 12800000;            // NN*128
  float* hC   = hA;                       // reuse (NN*64 needed)

  hipMemsetAsync(deg, 0, NN * sizeof(int), stream);
  deg_kernel<<<1024, 256, 0, stream>>>(dst, deg);
  dinv_kernel<<<(NN + 255) / 256, 256, 0, stream>>>(deg, dinv);

  // layer 1: h1 = x@W1 ; agg1 = dinv^2*h1 + b1 ; edges
  gemm_kernel<128, false><<<NN / 32, 256, 0, stream>>>(x, W1, b1, dinv, hA, aggA);
  scatter_kernel<128><<<2048, 256, 0, stream>>>(src, dst, dinv, hA, aggA);

  // layer 2: h2 = relu(agg1)@W2 ; agg2 = dinv^2*h2 + b2 ; edges
  gemm_kernel<128, true><<<NN / 32, 256, 0, stream>>>(aggA, W2, b2, dinv, hB, aggB);
  scatter_kernel<128><<<2048, 256, 0, stream>>>(src, dst, dinv, hB, aggB);

  // layer 3: h3 = relu(agg2)@W3 ; out = dinv^2*h3 + b3 ; edges (no relu)
  gemm_kernel<64, true><<<NN / 32, 256, 0, stream>>>(aggB, W3, b3, dinv, hC, out);
  scatter_kernel<64><<<2048, 256, 0, stream>>>(src, dst, dinv, hC, out);
}

// Round 3
// 557.966 us; speedup vs baseline: 1.5485x; 1.5485x over previous
//
#include <hip/hip_runtime.h>

#define NN 100000
#define NE 600000

// ---------------- degree (int atomics) ----------------
__global__ void deg_kernel(const int* __restrict__ dst, int* __restrict__ deg) {
  int i = blockIdx.x * blockDim.x + threadIdx.x;
  int n = gridDim.x * blockDim.x;
  for (; i < NE; i += n) atomicAdd(&deg[dst[i]], 1);
}

__global__ void dinv_kernel(const int* __restrict__ deg, float* __restrict__ dinv) {
  int i = blockIdx.x * blockDim.x + threadIdx.x;
  if (i < NN) dinv[i] = rsqrtf((float)deg[i] + 1.0f);
}

// ---------------- exclusive scan of deg -> off (single 1024-thread block) ----------------
__global__ __launch_bounds__(1024) void scan_kernel(const int* __restrict__ deg,
                                                    int* __restrict__ off) {
  __shared__ int wsum[16];
  __shared__ int carry_s;
  const int t = threadIdx.x, lane = t & 63, wv = t >> 6;
  if (t == 0) carry_s = 0;
  __syncthreads();
  for (int base = 0; base < NN; base += 1024) {
    int i = base + t;
    int v = (i < NN) ? deg[i] : 0;
    int sv = v;
    #pragma unroll
    for (int d = 1; d < 64; d <<= 1) {
      int u = __shfl_up(sv, d, 64);
      if (lane >= d) sv += u;
    }
    if (lane == 63) wsum[wv] = sv;
    __syncthreads();
    if (t < 16) {
      int w0 = wsum[t];
      #pragma unroll
      for (int d = 1; d < 16; d <<= 1) {
        int u = __shfl_up(w0, d, 64);
        if (t >= d) w0 += u;
      }
      wsum[t] = w0;   // inclusive scan of wave sums
    }
    __syncthreads();
    int excl = carry_s + (wv ? wsum[wv - 1] : 0) + (sv - v);
    if (i < NN) off[i] = excl;
    __syncthreads();                 // everyone done with carry_s/wsum
    if (t == 0) carry_s += wsum[15];
    __syncthreads();                 // carry ready before wsum rewritten
  }
  if (t == 0) off[NN] = NE;
}

// ---------------- counting-sort fill: CSR edge list with precomputed coef ----------------
__global__ void fill_kernel(const int* __restrict__ src, const int* __restrict__ dst,
                            const float* __restrict__ dinv, const int* __restrict__ off,
                            int* __restrict__ cursor, int2* __restrict__ einfo) {
  int i = blockIdx.x * blockDim.x + threadIdx.x;
  int n = gridDim.x * blockDim.x;
  for (; i < NE; i += n) {
    int s = src[i], d = dst[i];
    int pos = off[d] + atomicAdd(&cursor[d], 1);
    einfo[pos] = make_int2(s, __float_as_int(dinv[s] * dinv[d]));
  }
}

// ---------------- GEMM: h = act(in) @ W ----------------
// in: [NN][128] f32. W: [128][NOUT]. Tile: 32 rows x NOUT cols per 256-thread block.
template<int NOUT, bool RELU>
__global__ __launch_bounds__(256) void gemm_kernel(
    const float* __restrict__ in, const float* __restrict__ W,
    float* __restrict__ h)
{
  __shared__ float xs[32 * 132];   // row-major tile, pad 132 (conflict-free)
  const int t = threadIdx.x;
  const int row0 = blockIdx.x * 32;

  const float4* in4 = (const float4*)in;
  #pragma unroll
  for (int q = 0; q < 4; ++q) {
    int f = t + q * 256;          // float4 id within tile
    int r = f >> 5;               // 0..31
    int c4 = f & 31;              // 0..31
    float4 v = in4[(size_t)(row0 + r) * 32 + c4];
    if (RELU) {
      v.x = fmaxf(v.x, 0.f); v.y = fmaxf(v.y, 0.f);
      v.z = fmaxf(v.z, 0.f); v.w = fmaxf(v.w, 0.f);
    }
    *(float4*)&xs[r * 132 + c4 * 4] = v;
  }
  __syncthreads();

  constexpr int TC  = NOUT / 4;        // float4 col-groups: 32 or 16
  constexpr int RPT = 32 * TC / 256;   // rows per thread: 4 or 2
  const int tc = t % TC;
  const int tr = t / TC;
  const float4* W4 = (const float4*)W;

  float4 acc[RPT];
  #pragma unroll
  for (int i = 0; i < RPT; ++i) acc[i] = make_float4(0.f, 0.f, 0.f, 0.f);

  #pragma unroll 4
  for (int k = 0; k < 128; ++k) {
    float4 wv = W4[k * TC + tc];       // global, L1/L2 resident
    #pragma unroll
    for (int i = 0; i < RPT; ++i) {
      float xv = xs[(tr * RPT + i) * 132 + k];
      acc[i].x = fmaf(xv, wv.x, acc[i].x);
      acc[i].y = fmaf(xv, wv.y, acc[i].y);
      acc[i].z = fmaf(xv, wv.z, acc[i].z);
      acc[i].w = fmaf(xv, wv.w, acc[i].w);
    }
  }

  float4* h4 = (float4*)h;
  #pragma unroll
  for (int i = 0; i < RPT; ++i) {
    int row = row0 + tr * RPT + i;
    h4[(size_t)row * TC + tc] = acc[i];
  }
}

// ---------------- aggregate: out[d] = b + dinv[d]^2*h[d] + sum_e coef*h[src_e] ----------------
// one wave per destination node
template<int NOUT>
__global__ __launch_bounds__(256) void agg_kernel(
    const float* __restrict__ h, const int* __restrict__ off,
    const int2* __restrict__ einfo, const float* __restrict__ dinv,
    const float* __restrict__ bias, float* __restrict__ out)
{
  const int w = (int)((blockIdx.x * 256 + threadIdx.x) >> 6);
  if (w >= NN) return;
  const int lane = threadIdx.x & 63;
  const int n0 = off[w], n1 = off[w + 1];
  const float di = dinv[w];
  const float di2 = di * di;
  if constexpr (NOUT == 128) {
    float a0 = fmaf(h[(size_t)w * 128 + lane],      di2, bias[lane]);
    float a1 = fmaf(h[(size_t)w * 128 + 64 + lane], di2, bias[64 + lane]);
    for (int e = n0; e < n1; ++e) {
      int2 sc = einfo[e];
      float c = __int_as_float(sc.y);
      const float* hp = h + (size_t)sc.x * 128;
      a0 = fmaf(hp[lane],      c, a0);
      a1 = fmaf(hp[64 + lane], c, a1);
    }
    out[(size_t)w * 128 + lane]      = a0;
    out[(size_t)w * 128 + 64 + lane] = a1;
  } else {
    float a0 = fmaf(h[(size_t)w * 64 + lane], di2, bias[lane]);
    for (int e = n0; e < n1; ++e) {
      int2 sc = einfo[e];
      a0 = fmaf(h[(size_t)sc.x * 64 + lane], __int_as_float(sc.y), a0);
    }
    out[(size_t)w * 64 + lane] = a0;
  }
}

extern "C" void kernel_launch(void* const* d_in, const int* in_sizes, int n_in,
                              void* d_out, int out_size, void* d_ws, size_t ws_size,
                              hipStream_t stream) {
  const float* x  = (const float*)d_in[0];
  const int*   ei = (const int*)d_in[1];
  const float* W1 = (const float*)d_in[2];
  const float* b1 = (const float*)d_in[3];
  const float* W2 = (const float*)d_in[4];
  const float* b2 = (const float*)d_in[5];
  const float* W3 = (const float*)d_in[6];
  const float* b3 = (const float*)d_in[7];
  float* out = (float*)d_out;

  const int* src = ei;
  const int* dst = ei + NE;

  // workspace layout (float elements)
  float* ws = (float*)d_ws;
  int*   deg    = (int*)ws;                     // NN
  float* dinv   = ws + NN;                      // NN
  int*   off    = (int*)(ws + 2 * NN);          // NN+4 (padded)
  int*   cursor = (int*)(ws + 3 * NN + 4);      // NN
  int2*  einfo  = (int2*)(ws + 4 * NN + 4);     // NE int2 (8B-aligned)
  float* buf1   = ws + 4 * NN + 4 + 2 * NE;     // NN*128 (16B-aligned)
  float* buf2   = buf1 + (size_t)NN * 128;      // NN*128

  hipMemsetAsync(deg, 0, NN * sizeof(int), stream);
  hipMemsetAsync(cursor, 0, NN * sizeof(int), stream);
  deg_kernel<<<1024, 256, 0, stream>>>(dst, deg);
  dinv_kernel<<<(NN + 255) / 256, 256, 0, stream>>>(deg, dinv);
  scan_kernel<<<1, 1024, 0, stream>>>(deg, off);
  fill_kernel<<<1024, 256, 0, stream>>>(src, dst, dinv, off, cursor, einfo);

  const int AGG_BLOCKS = (NN * 64 + 255) / 256;   // one wave per node

  // layer 1
  gemm_kernel<128, false><<<NN / 32, 256, 0, stream>>>(x, W1, buf1);
  agg_kernel<128><<<AGG_BLOCKS, 256, 0, stream>>>(buf1, off, einfo, dinv, b1, buf2);
  // layer 2
  gemm_kernel<128, true><<<NN / 32, 256, 0, stream>>>(buf2, W2, buf1);
  agg_kernel<128><<<AGG_BLOCKS, 256, 0, stream>>>(buf1, off, einfo, dinv, b2, buf2);
  // layer 3
  gemm_kernel<64, true><<<NN / 32, 256, 0, stream>>>(buf2, W3, buf1);
  agg_kernel<64><<<AGG_BLOCKS, 256, 0, stream>>>(buf1, off, einfo, dinv, b3, out);
}

// Round 5
// 475.471 us; speedup vs baseline: 1.8171x; 1.1735x over previous
//
#include <hip/hip_runtime.h>

#define NN 100000
#define NE 600000
#define NB_SCAN 98   // 98 * 1024 = 100352 >= NN

// ---------------- degree (int atomics) ----------------
__global__ void deg_kernel(const int* __restrict__ dst, int* __restrict__ deg) {
  int i = blockIdx.x * blockDim.x + threadIdx.x;
  int n = gridDim.x * blockDim.x;
  for (; i < NE; i += n) atomicAdd(&deg[dst[i]], 1);
}

__global__ void dinv_kernel(const int* __restrict__ deg, float* __restrict__ dinv) {
  int i = blockIdx.x * blockDim.x + threadIdx.x;
  if (i < NN) dinv[i] = rsqrtf((float)deg[i] + 1.0f);
}

// ---------------- hierarchical exclusive scan: deg -> off ----------------
// pass 1: per-block (1024 elems) exclusive scan + block sum
__global__ __launch_bounds__(1024) void scan_blocks(const int* __restrict__ deg,
                                                    int* __restrict__ off,
                                                    int* __restrict__ bsum) {
  __shared__ int wsum[16];
  const int t = threadIdx.x, lane = t & 63, wv = t >> 6;
  const int i = blockIdx.x * 1024 + t;
  int v = (i < NN) ? deg[i] : 0;
  int sv = v;
  #pragma unroll
  for (int d = 1; d < 64; d <<= 1) {
    int u = __shfl_up(sv, d, 64);
    if (lane >= d) sv += u;
  }
  if (lane == 63) wsum[wv] = sv;
  __syncthreads();
  if (t < 16) {
    int w0 = wsum[t];
    #pragma unroll
    for (int d = 1; d < 16; d <<= 1) {
      int u = __shfl_up(w0, d, 64);
      if (t >= d) w0 += u;
    }
    wsum[t] = w0;   // inclusive scan of wave sums
  }
  __syncthreads();
  int excl = (wv ? wsum[wv - 1] : 0) + (sv - v);
  if (i < NN) off[i] = excl;
  if (t == 0) bsum[blockIdx.x] = wsum[15];
}

// pass 2: exclusive scan of the 98 block sums (single small block)
__global__ __launch_bounds__(128) void scan_bsum(int* __restrict__ bsum) {
  __shared__ int ws0;
  const int t = threadIdx.x, lane = t & 63, wv = t >> 6;
  int v = (t < NB_SCAN) ? bsum[t] : 0;
  int sv = v;
  #pragma unroll
  for (int d = 1; d < 64; d <<= 1) {
    int u = __shfl_up(sv, d, 64);
    if (lane >= d) sv += u;
  }
  if (wv == 0 && lane == 63) ws0 = sv;
  __syncthreads();
  int excl = (wv ? ws0 : 0) + (sv - v);
  if (t < NB_SCAN) bsum[t] = excl;
}

// pass 3: add block prefix
__global__ __launch_bounds__(1024) void scan_add(int* __restrict__ off,
                                                 const int* __restrict__ bsum) {
  int i = blockIdx.x * 1024 + threadIdx.x;
  if (i < NN) off[i] += bsum[blockIdx.x];
  if (i == 0) off[NN] = NE;
}

// ---------------- counting-sort fill: CSR edge list with precomputed coef ----------------
__global__ void fill_kernel(const int* __restrict__ src, const int* __restrict__ dst,
                            const float* __restrict__ dinv, const int* __restrict__ off,
                            int* __restrict__ cursor, int2* __restrict__ einfo) {
  int i = blockIdx.x * blockDim.x + threadIdx.x;
  int n = gridDim.x * blockDim.x;
  for (; i < NE; i += n) {
    int s = src[i], d = dst[i];
    int pos = off[d] + atomicAdd(&cursor[d], 1);
    einfo[pos] = make_int2(s, __float_as_int(dinv[s] * dinv[d]));
  }
}

// ---------------- GEMM: h = act(in) @ W ----------------
// in: [NN][128] f32. W: [128][NOUT]. Tile: 32 rows x NOUT cols per 256-thread block.
template<int NOUT, bool RELU>
__global__ __launch_bounds__(256) void gemm_kernel(
    const float* __restrict__ in, const float* __restrict__ W,
    float* __restrict__ h)
{
  __shared__ float xs[32 * 132];   // row-major tile, pad 132 (conflict-free)
  const int t = threadIdx.x;
  const int row0 = blockIdx.x * 32;

  const float4* in4 = (const float4*)in;
  #pragma unroll
  for (int q = 0; q < 4; ++q) {
    int f = t + q * 256;          // float4 id within tile
    int r = f >> 5;               // 0..31
    int c4 = f & 31;              // 0..31
    float4 v = in4[(size_t)(row0 + r) * 32 + c4];
    if (RELU) {
      v.x = fmaxf(v.x, 0.f); v.y = fmaxf(v.y, 0.f);
      v.z = fmaxf(v.z, 0.f); v.w = fmaxf(v.w, 0.f);
    }
    *(float4*)&xs[r * 132 + c4 * 4] = v;
  }
  __syncthreads();

  constexpr int TC  = NOUT / 4;        // float4 col-groups: 32 or 16
  constexpr int RPT = 32 * TC / 256;   // rows per thread: 4 or 2
  const int tc = t % TC;
  const int tr = t / TC;
  const float4* W4 = (const float4*)W;

  float4 acc[RPT];
  #pragma unroll
  for (int i = 0; i < RPT; ++i) acc[i] = make_float4(0.f, 0.f, 0.f, 0.f);

  #pragma unroll 4
  for (int k = 0; k < 128; ++k) {
    float4 wv = W4[k * TC + tc];       // global, L1/L2 resident
    #pragma unroll
    for (int i = 0; i < RPT; ++i) {
      float xv = xs[(tr * RPT + i) * 132 + k];
      acc[i].x = fmaf(xv, wv.x, acc[i].x);
      acc[i].y = fmaf(xv, wv.y, acc[i].y);
      acc[i].z = fmaf(xv, wv.z, acc[i].z);
      acc[i].w = fmaf(xv, wv.w, acc[i].w);
    }
  }

  float4* h4 = (float4*)h;
  #pragma unroll
  for (int i = 0; i < RPT; ++i) {
    int row = row0 + tr * RPT + i;
    h4[(size_t)row * TC + tc] = acc[i];
  }
}

// ---------------- aggregate: out[d] = b + dinv[d]^2*h[d] + sum_e coef*h[src_e] ----------------
// one wave per destination node
template<int NOUT>
__global__ __launch_bounds__(256) void agg_kernel(
    const float* __restrict__ h, const int* __restrict__ off,
    const int2* __restrict__ einfo, const float* __restrict__ dinv,
    const float* __restrict__ bias, float* __restrict__ out)
{
  const int w = (int)((blockIdx.x * 256 + threadIdx.x) >> 6);
  if (w >= NN) return;
  const int lane = threadIdx.x & 63;
  const int n0 = off[w], n1 = off[w + 1];
  const float di = dinv[w];
  const float di2 = di * di;
  if constexpr (NOUT == 128) {
    float a0 = fmaf(h[(size_t)w * 128 + lane],      di2, bias[lane]);
    float a1 = fmaf(h[(size_t)w * 128 + 64 + lane], di2, bias[64 + lane]);
    for (int e = n0; e < n1; ++e) {
      int2 sc = einfo[e];
      float c = __int_as_float(sc.y);
      const float* hp = h + (size_t)sc.x * 128;
      a0 = fmaf(hp[lane],      c, a0);
      a1 = fmaf(hp[64 + lane], c, a1);
    }
    out[(size_t)w * 128 + lane]      = a0;
    out[(size_t)w * 128 + 64 + lane] = a1;
  } else {
    float a0 = fmaf(h[(size_t)w * 64 + lane], di2, bias[lane]);
    for (int e = n0; e < n1; ++e) {
      int2 sc = einfo[e];
      a0 = fmaf(h[(size_t)sc.x * 64 + lane], __int_as_float(sc.y), a0);
    }
    out[(size_t)w * 64 + lane] = a0;
  }
}

extern "C" void kernel_launch(void* const* d_in, const int* in_sizes, int n_in,
                              void* d_out, int out_size, void* d_ws, size_t ws_size,
                              hipStream_t stream) {
  const float* x  = (const float*)d_in[0];
  const int*   ei = (const int*)d_in[1];
  const float* W1 = (const float*)d_in[2];
  const float* b1 = (const float*)d_in[3];
  const float* W2 = (const float*)d_in[4];
  const float* b2 = (const float*)d_in[5];
  const float* W3 = (const float*)d_in[6];
  const float* b3 = (const float*)d_in[7];
  float* out = (float*)d_out;

  const int* src = ei;
  const int* dst = ei + NE;

  // workspace layout (float elements)
  float* ws = (float*)d_ws;
  int*   deg    = (int*)ws;                     // NN
  float* dinv   = ws + NN;                      // NN
  int*   off    = (int*)(ws + 2 * NN);          // NN+1 (padded to 4)
  int*   cursor = (int*)(ws + 3 * NN + 4);      // NN
  int*   bsum   = (int*)(ws + 4 * NN + 4);      // 128
  int2*  einfo  = (int2*)(ws + 4 * NN + 132);   // NE int2 (8B-aligned)
  float* buf1   = ws + 4 * NN + 132 + 2 * NE;   // NN*128 (16B-aligned)
  float* buf2   = buf1 + (size_t)NN * 128;      // NN*128

  hipMemsetAsync(deg, 0, NN * sizeof(int), stream);
  hipMemsetAsync(cursor, 0, NN * sizeof(int), stream);
  deg_kernel<<<1024, 256, 0, stream>>>(dst, deg);
  dinv_kernel<<<(NN + 255) / 256, 256, 0, stream>>>(deg, dinv);
  scan_blocks<<<NB_SCAN, 1024, 0, stream>>>(deg, off, bsum);
  scan_bsum<<<1, 128, 0, stream>>>(bsum);
  scan_add<<<NB_SCAN, 1024, 0, stream>>>(off, bsum);
  fill_kernel<<<1024, 256, 0, stream>>>(src, dst, dinv, off, cursor, einfo);

  const int AGG_BLOCKS = (NN * 64 + 255) / 256;   // one wave per node

  // layer 1
  gemm_kernel<128, false><<<NN / 32, 256, 0, stream>>>(x, W1, buf1);
  agg_kernel<128><<<AGG_BLOCKS, 256, 0, stream>>>(buf1, off, einfo, dinv, b1, buf2);
  // layer 2
  gemm_kernel<128, true><<<NN / 32, 256, 0, stream>>>(buf2, W2, buf1);
  agg_kernel<128><<<AGG_BLOCKS, 256, 0, stream>>>(buf1, off, einfo, dinv, b2, buf2);
  // layer 3
  gemm_kernel<64, true><<<NN / 32, 256, 0, stream>>>(buf2, W3, buf1);
  agg_kernel<64><<<AGG_BLOCKS, 256, 0, stream>>>(buf1, off, einfo, dinv, b3, out);
}

// Round 6
// 453.351 us; speedup vs baseline: 1.9058x; 1.0488x over previous
//
#include <hip/hip_runtime.h>

#define NN 100000
#define NE 600000
#define NB_SCAN 98   // 98 * 1024 = 100352 >= NN

// bf16 helpers (RNE; inputs are finite, no NaN handling needed)
__device__ __forceinline__ unsigned short f2b(float f) {
  unsigned u = __float_as_uint(f);
  unsigned r = u + 0x7fffu + ((u >> 16) & 1u);
  return (unsigned short)(r >> 16);
}
__device__ __forceinline__ float b2f(unsigned short s) {
  return __uint_as_float((unsigned)s << 16);
}
__device__ __forceinline__ float bf_lo(unsigned p) { return __uint_as_float(p << 16); }
__device__ __forceinline__ float bf_hi(unsigned p) { return __uint_as_float(p & 0xffff0000u); }

// ---------------- degree (int atomics) ----------------
__global__ void deg_kernel(const int* __restrict__ dst, int* __restrict__ deg) {
  int i = blockIdx.x * blockDim.x + threadIdx.x;
  int n = gridDim.x * blockDim.x;
  for (; i < NE; i += n) atomicAdd(&deg[dst[i]], 1);
}

__global__ void dinv_kernel(const int* __restrict__ deg, float* __restrict__ dinv) {
  int i = blockIdx.x * blockDim.x + threadIdx.x;
  if (i < NN) dinv[i] = rsqrtf((float)deg[i] + 1.0f);
}

// ---------------- hierarchical exclusive scan: deg -> off ----------------
__global__ __launch_bounds__(1024) void scan_blocks(const int* __restrict__ deg,
                                                    int* __restrict__ off,
                                                    int* __restrict__ bsum) {
  __shared__ int wsum[16];
  const int t = threadIdx.x, lane = t & 63, wv = t >> 6;
  const int i = blockIdx.x * 1024 + t;
  int v = (i < NN) ? deg[i] : 0;
  int sv = v;
  #pragma unroll
  for (int d = 1; d < 64; d <<= 1) {
    int u = __shfl_up(sv, d, 64);
    if (lane >= d) sv += u;
  }
  if (lane == 63) wsum[wv] = sv;
  __syncthreads();
  if (t < 16) {
    int w0 = wsum[t];
    #pragma unroll
    for (int d = 1; d < 16; d <<= 1) {
      int u = __shfl_up(w0, d, 64);
      if (t >= d) w0 += u;
    }
    wsum[t] = w0;   // inclusive scan of wave sums
  }
  __syncthreads();
  int excl = (wv ? wsum[wv - 1] : 0) + (sv - v);
  if (i < NN) off[i] = excl;
  if (t == 0) bsum[blockIdx.x] = wsum[15];
}

__global__ __launch_bounds__(128) void scan_bsum(int* __restrict__ bsum) {
  __shared__ int ws0;
  const int t = threadIdx.x, lane = t & 63, wv = t >> 6;
  int v = (t < NB_SCAN) ? bsum[t] : 0;
  int sv = v;
  #pragma unroll
  for (int d = 1; d < 64; d <<= 1) {
    int u = __shfl_up(sv, d, 64);
    if (lane >= d) sv += u;
  }
  if (wv == 0 && lane == 63) ws0 = sv;
  __syncthreads();
  int excl = (wv ? ws0 : 0) + (sv - v);
  if (t < NB_SCAN) bsum[t] = excl;
}

__global__ __launch_bounds__(1024) void scan_add(int* __restrict__ off,
                                                 const int* __restrict__ bsum) {
  int i = blockIdx.x * 1024 + threadIdx.x;
  if (i < NN) off[i] += bsum[blockIdx.x];
  if (i == 0) off[NN] = NE;
}

// ---------------- counting-sort fill: CSR edge list with precomputed coef ----------------
__global__ void fill_kernel(const int* __restrict__ src, const int* __restrict__ dst,
                            const float* __restrict__ dinv, const int* __restrict__ off,
                            int* __restrict__ cursor, int2* __restrict__ einfo) {
  int i = blockIdx.x * blockDim.x + threadIdx.x;
  int n = gridDim.x * blockDim.x;
  for (; i < NE; i += n) {
    int s = src[i], d = dst[i];
    int pos = off[d] + atomicAdd(&cursor[d], 1);
    einfo[pos] = make_int2(s, __float_as_int(dinv[s] * dinv[d]));
  }
}

// ---------------- GEMM: h = act(in) @ W  (h stored bf16) ----------------
// in: [NN][128] f32. W: [128][NOUT]. Tile: 32 rows x NOUT cols per 256-thread block.
template<int NOUT, bool RELU>
__global__ __launch_bounds__(256) void gemm_kernel(
    const float* __restrict__ in, const float* __restrict__ W,
    unsigned short* __restrict__ h)
{
  __shared__ float xs[32 * 132];   // row-major tile, pad 132 (conflict-free)
  const int t = threadIdx.x;
  const int row0 = blockIdx.x * 32;

  const float4* in4 = (const float4*)in;
  #pragma unroll
  for (int q = 0; q < 4; ++q) {
    int f = t + q * 256;          // float4 id within tile
    int r = f >> 5;               // 0..31
    int c4 = f & 31;              // 0..31
    float4 v = in4[(size_t)(row0 + r) * 32 + c4];
    if (RELU) {
      v.x = fmaxf(v.x, 0.f); v.y = fmaxf(v.y, 0.f);
      v.z = fmaxf(v.z, 0.f); v.w = fmaxf(v.w, 0.f);
    }
    *(float4*)&xs[r * 132 + c4 * 4] = v;
  }
  __syncthreads();

  constexpr int TC  = NOUT / 4;        // float4 col-groups: 32 or 16
  constexpr int RPT = 32 * TC / 256;   // rows per thread: 4 or 2
  const int tc = t % TC;
  const int tr = t / TC;
  const float4* W4 = (const float4*)W;

  float4 acc[RPT];
  #pragma unroll
  for (int i = 0; i < RPT; ++i) acc[i] = make_float4(0.f, 0.f, 0.f, 0.f);

  #pragma unroll 4
  for (int k = 0; k < 128; ++k) {
    float4 wv = W4[k * TC + tc];       // global, L1/L2 resident
    #pragma unroll
    for (int i = 0; i < RPT; ++i) {
      float xv = xs[(tr * RPT + i) * 132 + k];
      acc[i].x = fmaf(xv, wv.x, acc[i].x);
      acc[i].y = fmaf(xv, wv.y, acc[i].y);
      acc[i].z = fmaf(xv, wv.z, acc[i].z);
      acc[i].w = fmaf(xv, wv.w, acc[i].w);
    }
  }

  ushort4* h4 = (ushort4*)h;
  #pragma unroll
  for (int i = 0; i < RPT; ++i) {
    int row = row0 + tr * RPT + i;
    float4 a = acc[i];
    ushort4 s;
    s.x = f2b(a.x); s.y = f2b(a.y); s.z = f2b(a.z); s.w = f2b(a.w);
    h4[(size_t)row * TC + tc] = s;
  }
}

// ---------------- aggregate: out[d] = b + dinv[d]^2*h[d] + sum_e coef*h[src_e] ----------------
// one wave per destination node; h is bf16, accumulation f32
template<int NOUT>
__global__ __launch_bounds__(256) void agg_kernel(
    const unsigned short* __restrict__ h, const int* __restrict__ off,
    const int2* __restrict__ einfo, const float* __restrict__ dinv,
    const float* __restrict__ bias, float* __restrict__ out)
{
  const int w = (int)((blockIdx.x * 256 + threadIdx.x) >> 6);
  if (w >= NN) return;
  const int lane = threadIdx.x & 63;
  const int n0 = off[w], n1 = off[w + 1];
  const float di = dinv[w];
  const float di2 = di * di;
  if constexpr (NOUT == 128) {
    // lane handles cols 2*lane, 2*lane+1 (one uint = 2 bf16 per lane)
    unsigned pw = ((const unsigned*)(h + (size_t)w * 128))[lane];
    float2 bv = ((const float2*)bias)[lane];
    float a0 = fmaf(bf_lo(pw), di2, bv.x);
    float a1 = fmaf(bf_hi(pw), di2, bv.y);
    for (int e = n0; e < n1; ++e) {
      int2 sc = einfo[e];
      float c = __int_as_float(sc.y);
      unsigned p = ((const unsigned*)(h + (size_t)sc.x * 128))[lane];
      a0 = fmaf(bf_lo(p), c, a0);
      a1 = fmaf(bf_hi(p), c, a1);
    }
    float2 o; o.x = a0; o.y = a1;
    ((float2*)out)[(size_t)w * 64 + lane] = o;
  } else {
    float a0 = fmaf(b2f(h[(size_t)w * 64 + lane]), di2, bias[lane]);
    for (int e = n0; e < n1; ++e) {
      int2 sc = einfo[e];
      a0 = fmaf(b2f(h[(size_t)sc.x * 64 + lane]), __int_as_float(sc.y), a0);
    }
    out[(size_t)w * 64 + lane] = a0;
  }
}

extern "C" void kernel_launch(void* const* d_in, const int* in_sizes, int n_in,
                              void* d_out, int out_size, void* d_ws, size_t ws_size,
                              hipStream_t stream) {
  const float* x  = (const float*)d_in[0];
  const int*   ei = (const int*)d_in[1];
  const float* W1 = (const float*)d_in[2];
  const float* b1 = (const float*)d_in[3];
  const float* W2 = (const float*)d_in[4];
  const float* b2 = (const float*)d_in[5];
  const float* W3 = (const float*)d_in[6];
  const float* b3 = (const float*)d_in[7];
  float* out = (float*)d_out;

  const int* src = ei;
  const int* dst = ei + NE;

  // workspace layout (float elements)
  float* ws = (float*)d_ws;
  int*   deg    = (int*)ws;                     // NN
  float* dinv   = ws + NN;                      // NN
  int*   off    = (int*)(ws + 2 * NN);          // NN+1 (padded to 4)
  int*   cursor = (int*)(ws + 3 * NN + 4);      // NN
  int*   bsum   = (int*)(ws + 4 * NN + 4);      // 128
  int2*  einfo  = (int2*)(ws + 4 * NN + 132);   // NE int2 (8B-aligned)
  unsigned short* hbuf = (unsigned short*)(ws + 4 * NN + 132 + 2 * NE); // NN*128 bf16 (16B-aligned)
  float* aggbuf = ws + 4 * NN + 132 + 2 * NE + (size_t)NN * 64;         // NN*128 f32

  hipMemsetAsync(deg, 0, NN * sizeof(int), stream);
  hipMemsetAsync(cursor, 0, NN * sizeof(int), stream);
  deg_kernel<<<1024, 256, 0, stream>>>(dst, deg);
  dinv_kernel<<<(NN + 255) / 256, 256, 0, stream>>>(deg, dinv);
  scan_blocks<<<NB_SCAN, 1024, 0, stream>>>(deg, off, bsum);
  scan_bsum<<<1, 128, 0, stream>>>(bsum);
  scan_add<<<NB_SCAN, 1024, 0, stream>>>(off, bsum);
  fill_kernel<<<1024, 256, 0, stream>>>(src, dst, dinv, off, cursor, einfo);

  const int AGG_BLOCKS = (NN * 64 + 255) / 256;   // one wave per node

  // layer 1
  gemm_kernel<128, false><<<NN / 32, 256, 0, stream>>>(x, W1, hbuf);
  agg_kernel<128><<<AGG_BLOCKS, 256, 0, stream>>>(hbuf, off, einfo, dinv, b1, aggbuf);
  // layer 2
  gemm_kernel<128, true><<<NN / 32, 256, 0, stream>>>(aggbuf, W2, hbuf);
  agg_kernel<128><<<AGG_BLOCKS, 256, 0, stream>>>(hbuf, off, einfo, dinv, b2, aggbuf);
  // layer 3
  gemm_kernel<64, true><<<NN / 32, 256, 0, stream>>>(aggbuf, W3, hbuf);
  agg_kernel<64><<<AGG_BLOCKS, 256, 0, stream>>>(hbuf, off, einfo, dinv, b3, out);
}

// Round 7
// 373.865 us; speedup vs baseline: 2.3110x; 1.2126x over previous
//
#include <hip/hip_runtime.h>

#define NN 100000
#define NE 600000
#define NB_SCAN 98   // 98 * 1024 = 100352 >= NN

// bf16 helpers (RNE; inputs are finite, no NaN handling needed)
__device__ __forceinline__ unsigned short f2b(float f) {
  unsigned u = __float_as_uint(f);
  unsigned r = u + 0x7fffu + ((u >> 16) & 1u);
  return (unsigned short)(r >> 16);
}
__device__ __forceinline__ float b2f(unsigned short s) {
  return __uint_as_float((unsigned)s << 16);
}
__device__ __forceinline__ float bf_lo(unsigned p) { return __uint_as_float(p << 16); }
__device__ __forceinline__ float bf_hi(unsigned p) { return __uint_as_float(p & 0xffff0000u); }

// ---------------- degree (int atomics) ----------------
__global__ void deg_kernel(const int* __restrict__ dst, int* __restrict__ deg) {
  int i = blockIdx.x * blockDim.x + threadIdx.x;
  int n = gridDim.x * blockDim.x;
  for (; i < NE; i += n) atomicAdd(&deg[dst[i]], 1);
}

__global__ void dinv_kernel(const int* __restrict__ deg, float* __restrict__ dinv) {
  int i = blockIdx.x * blockDim.x + threadIdx.x;
  if (i < NN) dinv[i] = rsqrtf((float)deg[i] + 1.0f);
}

// ---------------- hierarchical exclusive scan: deg -> off ----------------
__global__ __launch_bounds__(1024) void scan_blocks(const int* __restrict__ deg,
                                                    int* __restrict__ off,
                                                    int* __restrict__ bsum) {
  __shared__ int wsum[16];
  const int t = threadIdx.x, lane = t & 63, wv = t >> 6;
  const int i = blockIdx.x * 1024 + t;
  int v = (i < NN) ? deg[i] : 0;
  int sv = v;
  #pragma unroll
  for (int d = 1; d < 64; d <<= 1) {
    int u = __shfl_up(sv, d, 64);
    if (lane >= d) sv += u;
  }
  if (lane == 63) wsum[wv] = sv;
  __syncthreads();
  if (t < 16) {
    int w0 = wsum[t];
    #pragma unroll
    for (int d = 1; d < 16; d <<= 1) {
      int u = __shfl_up(w0, d, 64);
      if (t >= d) w0 += u;
    }
    wsum[t] = w0;   // inclusive scan of wave sums
  }
  __syncthreads();
  int excl = (wv ? wsum[wv - 1] : 0) + (sv - v);
  if (i < NN) off[i] = excl;
  if (t == 0) bsum[blockIdx.x] = wsum[15];
}

__global__ __launch_bounds__(128) void scan_bsum(int* __restrict__ bsum) {
  __shared__ int ws0;
  const int t = threadIdx.x, lane = t & 63, wv = t >> 6;
  int v = (t < NB_SCAN) ? bsum[t] : 0;
  int sv = v;
  #pragma unroll
  for (int d = 1; d < 64; d <<= 1) {
    int u = __shfl_up(sv, d, 64);
    if (lane >= d) sv += u;
  }
  if (wv == 0 && lane == 63) ws0 = sv;
  __syncthreads();
  int excl = (wv ? ws0 : 0) + (sv - v);
  if (t < NB_SCAN) bsum[t] = excl;
}

__global__ __launch_bounds__(1024) void scan_add(int* __restrict__ off,
                                                 const int* __restrict__ bsum) {
  int i = blockIdx.x * 1024 + threadIdx.x;
  if (i < NN) off[i] += bsum[blockIdx.x];
  if (i == 0) off[NN] = NE;
}

// ---------------- counting-sort fill: CSR edge list with precomputed coef ----------------
__global__ void fill_kernel(const int* __restrict__ src, const int* __restrict__ dst,
                            const float* __restrict__ dinv, const int* __restrict__ off,
                            int* __restrict__ cursor, int2* __restrict__ einfo) {
  int i = blockIdx.x * blockDim.x + threadIdx.x;
  int n = gridDim.x * blockDim.x;
  for (; i < NE; i += n) {
    int s = src[i], d = dst[i];
    int pos = off[d] + atomicAdd(&cursor[d], 1);
    einfo[pos] = make_int2(s, __float_as_int(dinv[s] * dinv[d]));
  }
}

// ---------------- GEMM: h = act(in) @ W  (h stored bf16) ----------------
// in: [NN][128] f32. W: [128][NOUT]. Tile: 32 rows x NOUT cols per 256-thread block.
template<int NOUT, bool RELU>
__global__ __launch_bounds__(256) void gemm_kernel(
    const float* __restrict__ in, const float* __restrict__ W,
    unsigned short* __restrict__ h)
{
  __shared__ float xs[32 * 132];   // row-major tile, pad 132 (conflict-free)
  const int t = threadIdx.x;
  const int row0 = blockIdx.x * 32;

  const float4* in4 = (const float4*)in;
  #pragma unroll
  for (int q = 0; q < 4; ++q) {
    int f = t + q * 256;          // float4 id within tile
    int r = f >> 5;               // 0..31
    int c4 = f & 31;              // 0..31
    float4 v = in4[(size_t)(row0 + r) * 32 + c4];
    if (RELU) {
      v.x = fmaxf(v.x, 0.f); v.y = fmaxf(v.y, 0.f);
      v.z = fmaxf(v.z, 0.f); v.w = fmaxf(v.w, 0.f);
    }
    *(float4*)&xs[r * 132 + c4 * 4] = v;
  }
  __syncthreads();

  constexpr int TC  = NOUT / 4;        // float4 col-groups: 32 or 16
  constexpr int RPT = 32 * TC / 256;   // rows per thread: 4 or 2
  const int tc = t % TC;
  const int tr = t / TC;
  const float4* W4 = (const float4*)W;

  float4 acc[RPT];
  #pragma unroll
  for (int i = 0; i < RPT; ++i) acc[i] = make_float4(0.f, 0.f, 0.f, 0.f);

  #pragma unroll 4
  for (int k = 0; k < 128; ++k) {
    float4 wv = W4[k * TC + tc];       // global, L1/L2 resident
    #pragma unroll
    for (int i = 0; i < RPT; ++i) {
      float xv = xs[(tr * RPT + i) * 132 + k];
      acc[i].x = fmaf(xv, wv.x, acc[i].x);
      acc[i].y = fmaf(xv, wv.y, acc[i].y);
      acc[i].z = fmaf(xv, wv.z, acc[i].z);
      acc[i].w = fmaf(xv, wv.w, acc[i].w);
    }
  }

  ushort4* h4 = (ushort4*)h;
  #pragma unroll
  for (int i = 0; i < RPT; ++i) {
    int row = row0 + tr * RPT + i;
    float4 a = acc[i];
    ushort4 s;
    s.x = f2b(a.x); s.y = f2b(a.y); s.z = f2b(a.z); s.w = f2b(a.w);
    h4[(size_t)row * TC + tc] = s;
  }
}

// ---------------- aggregate: out[d] = b + dinv[d]^2*h[d] + sum_e coef*h[src_e] ----------------
// one wave per destination node; h bf16, f32 accum; 8-wide ILP gather groups
// (clamped idx + zero coef for tail -> no serial remainder; dup loads L1-hit)
template<int NOUT>
__global__ __launch_bounds__(256) void agg_kernel(
    const unsigned short* __restrict__ h, const int* __restrict__ off,
    const int2* __restrict__ einfo, const float* __restrict__ dinv,
    const float* __restrict__ bias, float* __restrict__ out)
{
  const int w = (int)((blockIdx.x * 256 + threadIdx.x) >> 6);
  if (w >= NN) return;
  const int lane = threadIdx.x & 63;
  const int n0 = off[w], n1 = off[w + 1];
  const float di = dinv[w];
  const float di2 = di * di;
  if constexpr (NOUT == 128) {
    const unsigned* hu = (const unsigned*)h;   // 2 bf16 per uint, 64 uints/row
    unsigned pw = hu[(size_t)w * 64 + lane];
    float2 bv = ((const float2*)bias)[lane];
    float a0 = fmaf(bf_lo(pw), di2, bv.x);
    float a1 = fmaf(bf_hi(pw), di2, bv.y);
    for (int e = n0; e < n1; e += 8) {
      int   idx[8];
      float cf[8];
      unsigned q[8];
      #pragma unroll
      for (int k = 0; k < 8; ++k) {
        int ee = e + k;
        bool ok = ee < n1;
        int2 sc = einfo[ok ? ee : n0];
        idx[k] = sc.x;
        cf[k]  = ok ? __int_as_float(sc.y) : 0.f;
      }
      #pragma unroll
      for (int k = 0; k < 8; ++k) q[k] = hu[(size_t)idx[k] * 64 + lane];
      #pragma unroll
      for (int k = 0; k < 8; ++k) {
        a0 = fmaf(bf_lo(q[k]), cf[k], a0);
        a1 = fmaf(bf_hi(q[k]), cf[k], a1);
      }
    }
    float2 o; o.x = a0; o.y = a1;
    ((float2*)out)[(size_t)w * 64 + lane] = o;
  } else {
    unsigned short pw = h[(size_t)w * 64 + lane];
    float a0 = fmaf(b2f(pw), di2, bias[lane]);
    for (int e = n0; e < n1; e += 8) {
      int   idx[8];
      float cf[8];
      unsigned short q[8];
      #pragma unroll
      for (int k = 0; k < 8; ++k) {
        int ee = e + k;
        bool ok = ee < n1;
        int2 sc = einfo[ok ? ee : n0];
        idx[k] = sc.x;
        cf[k]  = ok ? __int_as_float(sc.y) : 0.f;
      }
      #pragma unroll
      for (int k = 0; k < 8; ++k) q[k] = h[(size_t)idx[k] * 64 + lane];
      #pragma unroll
      for (int k = 0; k < 8; ++k) a0 = fmaf(b2f(q[k]), cf[k], a0);
    }
    out[(size_t)w * 64 + lane] = a0;
  }
}

extern "C" void kernel_launch(void* const* d_in, const int* in_sizes, int n_in,
                              void* d_out, int out_size, void* d_ws, size_t ws_size,
                              hipStream_t stream) {
  const float* x  = (const float*)d_in[0];
  const int*   ei = (const int*)d_in[1];
  const float* W1 = (const float*)d_in[2];
  const float* b1 = (const float*)d_in[3];
  const float* W2 = (const float*)d_in[4];
  const float* b2 = (const float*)d_in[5];
  const float* W3 = (const float*)d_in[6];
  const float* b3 = (const float*)d_in[7];
  float* out = (float*)d_out;

  const int* src = ei;
  const int* dst = ei + NE;

  // workspace layout (float elements)
  float* ws = (float*)d_ws;
  int*   deg    = (int*)ws;                     // NN
  float* dinv   = ws + NN;                      // NN
  int*   off    = (int*)(ws + 2 * NN);          // NN+1 (padded to 4)
  int*   cursor = (int*)(ws + 3 * NN + 4);      // NN
  int*   bsum   = (int*)(ws + 4 * NN + 4);      // 128
  int2*  einfo  = (int2*)(ws + 4 * NN + 132);   // NE int2 (8B-aligned)
  unsigned short* hbuf = (unsigned short*)(ws + 4 * NN + 132 + 2 * NE); // NN*128 bf16 (16B-aligned)
  float* aggbuf = ws + 4 * NN + 132 + 2 * NE + (size_t)NN * 64;         // NN*128 f32

  hipMemsetAsync(deg, 0, NN * sizeof(int), stream);
  hipMemsetAsync(cursor, 0, NN * sizeof(int), stream);
  deg_kernel<<<1024, 256, 0, stream>>>(dst, deg);
  dinv_kernel<<<(NN + 255) / 256, 256, 0, stream>>>(deg, dinv);
  scan_blocks<<<NB_SCAN, 1024, 0, stream>>>(deg, off, bsum);
  scan_bsum<<<1, 128, 0, stream>>>(bsum);
  scan_add<<<NB_SCAN, 1024, 0, stream>>>(off, bsum);
  fill_kernel<<<1024, 256, 0, stream>>>(src, dst, dinv, off, cursor, einfo);

  const int AGG_BLOCKS = (NN * 64 + 255) / 256;   // one wave per node

  // layer 1
  gemm_kernel<128, false><<<NN / 32, 256, 0, stream>>>(x, W1, hbuf);
  agg_kernel<128><<<AGG_BLOCKS, 256, 0, stream>>>(hbuf, off, einfo, dinv, b1, aggbuf);
  // layer 2
  gemm_kernel<128, true><<<NN / 32, 256, 0, stream>>>(aggbuf, W2, hbuf);
  agg_kernel<128><<<AGG_BLOCKS, 256, 0, stream>>>(hbuf, off, einfo, dinv, b2, aggbuf);
  // layer 3
  gemm_kernel<64, true><<<NN / 32, 256, 0, stream>>>(aggbuf, W3, hbuf);
  agg_kernel<64><<<AGG_BLOCKS, 256, 0, stream>>>(hbuf, off, einfo, dinv, b3, out);
}

// Round 8
// 332.226 us; speedup vs baseline: 2.6006x; 1.1253x over previous
//
#include <hip/hip_runtime.h>

#define NN 100000
#define NE 600000
#define NB_SCAN 98   // 98 * 1024 = 100352 >= NN

// bf16 helpers (RNE; inputs are finite, no NaN handling needed)
__device__ __forceinline__ unsigned short f2b(float f) {
  unsigned u = __float_as_uint(f);
  unsigned r = u + 0x7fffu + ((u >> 16) & 1u);
  return (unsigned short)(r >> 16);
}
__device__ __forceinline__ float b2f(unsigned short s) {
  return __uint_as_float((unsigned)s << 16);
}
__device__ __forceinline__ float bf_lo(unsigned p) { return __uint_as_float(p << 16); }
__device__ __forceinline__ float bf_hi(unsigned p) { return __uint_as_float(p & 0xffff0000u); }

// ---------------- degree (int atomics) ----------------
__global__ void deg_kernel(const int* __restrict__ dst, int* __restrict__ deg) {
  int i = blockIdx.x * blockDim.x + threadIdx.x;
  int n = gridDim.x * blockDim.x;
  for (; i < NE; i += n) atomicAdd(&deg[dst[i]], 1);
}

__global__ void dinv_kernel(const int* __restrict__ deg, float* __restrict__ dinv) {
  int i = blockIdx.x * blockDim.x + threadIdx.x;
  if (i < NN) dinv[i] = rsqrtf((float)deg[i] + 1.0f);
}

// ---------------- hierarchical exclusive scan: deg -> off ----------------
__global__ __launch_bounds__(1024) void scan_blocks(const int* __restrict__ deg,
                                                    int* __restrict__ off,
                                                    int* __restrict__ bsum) {
  __shared__ int wsum[16];
  const int t = threadIdx.x, lane = t & 63, wv = t >> 6;
  const int i = blockIdx.x * 1024 + t;
  int v = (i < NN) ? deg[i] : 0;
  int sv = v;
  #pragma unroll
  for (int d = 1; d < 64; d <<= 1) {
    int u = __shfl_up(sv, d, 64);
    if (lane >= d) sv += u;
  }
  if (lane == 63) wsum[wv] = sv;
  __syncthreads();
  if (t < 16) {
    int w0 = wsum[t];
    #pragma unroll
    for (int d = 1; d < 16; d <<= 1) {
      int u = __shfl_up(w0, d, 64);
      if (t >= d) w0 += u;
    }
    wsum[t] = w0;   // inclusive scan of wave sums
  }
  __syncthreads();
  int excl = (wv ? wsum[wv - 1] : 0) + (sv - v);
  if (i < NN) off[i] = excl;
  if (t == 0) bsum[blockIdx.x] = wsum[15];
}

__global__ __launch_bounds__(128) void scan_bsum(int* __restrict__ bsum) {
  __shared__ int ws0;
  const int t = threadIdx.x, lane = t & 63, wv = t >> 6;
  int v = (t < NB_SCAN) ? bsum[t] : 0;
  int sv = v;
  #pragma unroll
  for (int d = 1; d < 64; d <<= 1) {
    int u = __shfl_up(sv, d, 64);
    if (lane >= d) sv += u;
  }
  if (wv == 0 && lane == 63) ws0 = sv;
  __syncthreads();
  int excl = (wv ? ws0 : 0) + (sv - v);
  if (t < NB_SCAN) bsum[t] = excl;
}

__global__ __launch_bounds__(1024) void scan_add(int* __restrict__ off,
                                                 const int* __restrict__ bsum) {
  int i = blockIdx.x * 1024 + threadIdx.x;
  if (i < NN) off[i] += bsum[blockIdx.x];
  if (i == 0) off[NN] = NE;
}

// ---------------- counting-sort fill: CSR edge list with precomputed coef ----------------
__global__ void fill_kernel(const int* __restrict__ src, const int* __restrict__ dst,
                            const float* __restrict__ dinv, const int* __restrict__ off,
                            int* __restrict__ cursor, int2* __restrict__ einfo) {
  int i = blockIdx.x * blockDim.x + threadIdx.x;
  int n = gridDim.x * blockDim.x;
  for (; i < NE; i += n) {
    int s = src[i], d = dst[i];
    int pos = off[d] + atomicAdd(&cursor[d], 1);
    einfo[pos] = make_int2(s, __float_as_int(dinv[s] * dinv[d]));
  }
}

// ---------------- GEMM: h = act(in) @ W  (h stored bf16) ----------------
// 64-row x NOUT-col tile per 256-thread block; k-unroll 4 with b128 LDS reads.
template<int NOUT, bool RELU>
__global__ __launch_bounds__(256) void gemm_kernel(
    const float* __restrict__ in, const float* __restrict__ W,
    unsigned short* __restrict__ h)
{
  __shared__ float xs[64 * 132];   // row-major tile, pad 132 (2-way max on b128)
  const int t = threadIdx.x;
  const int row0 = blockIdx.x * 64;

  // stage 64x128 input tile (float4 loads, b128 LDS writes); clamp ragged tail
  const float4* in4 = (const float4*)in;
  #pragma unroll
  for (int q = 0; q < 8; ++q) {
    int f = t + q * 256;          // float4 id within tile
    int r = f >> 5;               // 0..63
    int c4 = f & 31;              // 0..31
    int rr = row0 + r; if (rr > NN - 1) rr = NN - 1;
    float4 v = in4[(size_t)rr * 32 + c4];
    if (RELU) {
      v.x = fmaxf(v.x, 0.f); v.y = fmaxf(v.y, 0.f);
      v.z = fmaxf(v.z, 0.f); v.w = fmaxf(v.w, 0.f);
    }
    *(float4*)&xs[r * 132 + c4 * 4] = v;
  }
  __syncthreads();

  constexpr int TC  = NOUT / 4;        // float4 col-groups: 32 or 16
  constexpr int RPT = 64 * TC / 256;   // rows per thread: 8 or 4
  const int tc = t % TC;
  const int tr = t / TC;
  const float4* W4 = (const float4*)W;

  float4 acc[RPT];
  #pragma unroll
  for (int i = 0; i < RPT; ++i) acc[i] = make_float4(0.f, 0.f, 0.f, 0.f);

  #pragma unroll 2
  for (int k = 0; k < 128; k += 4) {
    float4 wv0 = W4[(k + 0) * TC + tc];
    float4 wv1 = W4[(k + 1) * TC + tc];
    float4 wv2 = W4[(k + 2) * TC + tc];
    float4 wv3 = W4[(k + 3) * TC + tc];
    #pragma unroll
    for (int i = 0; i < RPT; ++i) {
      float4 xv = *(const float4*)&xs[(tr * RPT + i) * 132 + k];
      acc[i].x = fmaf(xv.x, wv0.x, acc[i].x);
      acc[i].y = fmaf(xv.x, wv0.y, acc[i].y);
      acc[i].z = fmaf(xv.x, wv0.z, acc[i].z);
      acc[i].w = fmaf(xv.x, wv0.w, acc[i].w);
      acc[i].x = fmaf(xv.y, wv1.x, acc[i].x);
      acc[i].y = fmaf(xv.y, wv1.y, acc[i].y);
      acc[i].z = fmaf(xv.y, wv1.z, acc[i].z);
      acc[i].w = fmaf(xv.y, wv1.w, acc[i].w);
      acc[i].x = fmaf(xv.z, wv2.x, acc[i].x);
      acc[i].y = fmaf(xv.z, wv2.y, acc[i].y);
      acc[i].z = fmaf(xv.z, wv2.z, acc[i].z);
      acc[i].w = fmaf(xv.z, wv2.w, acc[i].w);
      acc[i].x = fmaf(xv.w, wv3.x, acc[i].x);
      acc[i].y = fmaf(xv.w, wv3.y, acc[i].y);
      acc[i].z = fmaf(xv.w, wv3.z, acc[i].z);
      acc[i].w = fmaf(xv.w, wv3.w, acc[i].w);
    }
  }

  ushort4* h4 = (ushort4*)h;
  #pragma unroll
  for (int i = 0; i < RPT; ++i) {
    int row = row0 + tr * RPT + i;
    if (row < NN) {
      float4 a = acc[i];
      ushort4 s;
      s.x = f2b(a.x); s.y = f2b(a.y); s.z = f2b(a.z); s.w = f2b(a.w);
      h4[(size_t)row * TC + tc] = s;
    }
  }
}

// ---------------- aggregate: out[d] = b + dinv[d]^2*h[d] + sum_e coef*h[src_e] ----------------
// one wave per destination node; h bf16, f32 accum; 8-wide ILP gather groups
template<int NOUT>
__global__ __launch_bounds__(256) void agg_kernel(
    const unsigned short* __restrict__ h, const int* __restrict__ off,
    const int2* __restrict__ einfo, const float* __restrict__ dinv,
    const float* __restrict__ bias, float* __restrict__ out)
{
  const int w = (int)((blockIdx.x * 256 + threadIdx.x) >> 6);
  if (w >= NN) return;
  const int lane = threadIdx.x & 63;
  const int n0 = off[w], n1 = off[w + 1];
  const float di = dinv[w];
  const float di2 = di * di;
  if constexpr (NOUT == 128) {
    const unsigned* hu = (const unsigned*)h;   // 2 bf16 per uint, 64 uints/row
    unsigned pw = hu[(size_t)w * 64 + lane];
    float2 bv = ((const float2*)bias)[lane];
    float a0 = fmaf(bf_lo(pw), di2, bv.x);
    float a1 = fmaf(bf_hi(pw), di2, bv.y);
    for (int e = n0; e < n1; e += 8) {
      int   idx[8];
      float cf[8];
      unsigned q[8];
      #pragma unroll
      for (int k = 0; k < 8; ++k) {
        int ee = e + k;
        bool ok = ee < n1;
        int2 sc = einfo[ok ? ee : n0];
        idx[k] = sc.x;
        cf[k]  = ok ? __int_as_float(sc.y) : 0.f;
      }
      #pragma unroll
      for (int k = 0; k < 8; ++k) q[k] = hu[(size_t)idx[k] * 64 + lane];
      #pragma unroll
      for (int k = 0; k < 8; ++k) {
        a0 = fmaf(bf_lo(q[k]), cf[k], a0);
        a1 = fmaf(bf_hi(q[k]), cf[k], a1);
      }
    }
    float2 o; o.x = a0; o.y = a1;
    ((float2*)out)[(size_t)w * 64 + lane] = o;
  } else {
    unsigned short pw = h[(size_t)w * 64 + lane];
    float a0 = fmaf(b2f(pw), di2, bias[lane]);
    for (int e = n0; e < n1; e += 8) {
      int   idx[8];
      float cf[8];
      unsigned short q[8];
      #pragma unroll
      for (int k = 0; k < 8; ++k) {
        int ee = e + k;
        bool ok = ee < n1;
        int2 sc = einfo[ok ? ee : n0];
        idx[k] = sc.x;
        cf[k]  = ok ? __int_as_float(sc.y) : 0.f;
      }
      #pragma unroll
      for (int k = 0; k < 8; ++k) q[k] = h[(size_t)idx[k] * 64 + lane];
      #pragma unroll
      for (int k = 0; k < 8; ++k) a0 = fmaf(b2f(q[k]), cf[k], a0);
    }
    out[(size_t)w * 64 + lane] = a0;
  }
}

extern "C" void kernel_launch(void* const* d_in, const int* in_sizes, int n_in,
                              void* d_out, int out_size, void* d_ws, size_t ws_size,
                              hipStream_t stream) {
  const float* x  = (const float*)d_in[0];
  const int*   ei = (const int*)d_in[1];
  const float* W1 = (const float*)d_in[2];
  const float* b1 = (const float*)d_in[3];
  const float* W2 = (const float*)d_in[4];
  const float* b2 = (const float*)d_in[5];
  const float* W3 = (const float*)d_in[6];
  const float* b3 = (const float*)d_in[7];
  float* out = (float*)d_out;

  const int* src = ei;
  const int* dst = ei + NE;

  // workspace layout (float elements)
  float* ws = (float*)d_ws;
  int*   deg    = (int*)ws;                     // NN
  float* dinv   = ws + NN;                      // NN
  int*   off    = (int*)(ws + 2 * NN);          // NN+1 (padded to 4)
  int*   cursor = (int*)(ws + 3 * NN + 4);      // NN
  int*   bsum   = (int*)(ws + 4 * NN + 4);      // 128
  int2*  einfo  = (int2*)(ws + 4 * NN + 132);   // NE int2 (8B-aligned)
  unsigned short* hbuf = (unsigned short*)(ws + 4 * NN + 132 + 2 * NE); // NN*128 bf16 (16B-aligned)
  float* aggbuf = ws + 4 * NN + 132 + 2 * NE + (size_t)NN * 64;         // NN*128 f32

  hipMemsetAsync(deg, 0, NN * sizeof(int), stream);
  hipMemsetAsync(cursor, 0, NN * sizeof(int), stream);
  deg_kernel<<<1024, 256, 0, stream>>>(dst, deg);
  dinv_kernel<<<(NN + 255) / 256, 256, 0, stream>>>(deg, dinv);
  scan_blocks<<<NB_SCAN, 1024, 0, stream>>>(deg, off, bsum);
  scan_bsum<<<1, 128, 0, stream>>>(bsum);
  scan_add<<<NB_SCAN, 1024, 0, stream>>>(off, bsum);
  fill_kernel<<<1024, 256, 0, stream>>>(src, dst, dinv, off, cursor, einfo);

  const int AGG_BLOCKS = (NN * 64 + 255) / 256;   // one wave per node
  const int GEMM_BLOCKS = (NN + 63) / 64;

  // layer 1
  gemm_kernel<128, false><<<GEMM_BLOCKS, 256, 0, stream>>>(x, W1, hbuf);
  agg_kernel<128><<<AGG_BLOCKS, 256, 0, stream>>>(hbuf, off, einfo, dinv, b1, aggbuf);
  // layer 2
  gemm_kernel<128, true><<<GEMM_BLOCKS, 256, 0, stream>>>(aggbuf, W2, hbuf);
  agg_kernel<128><<<AGG_BLOCKS, 256, 0, stream>>>(hbuf, off, einfo, dinv, b2, aggbuf);
  // layer 3
  gemm_kernel<64, true><<<GEMM_BLOCKS, 256, 0, stream>>>(aggbuf, W3, hbuf);
  agg_kernel<64><<<AGG_BLOCKS, 256, 0, stream>>>(hbuf, off, einfo, dinv, b3, out);
}

// Round 9
// 293.237 us; speedup vs baseline: 2.9464x; 1.1330x over previous
//
#include <hip/hip_runtime.h>

#define NN 100000
#define NE 600000
#define NB_SCAN 98   // 98 * 1024 = 100352 >= NN

typedef __attribute__((ext_vector_type(8))) short short8v;   // 8 bf16 (4 VGPRs)
typedef __attribute__((ext_vector_type(4))) float float4v;   // MFMA acc

// bf16 helpers (RNE; inputs are finite)
__device__ __forceinline__ unsigned short f2b(float f) {
  unsigned u = __float_as_uint(f);
  unsigned r = u + 0x7fffu + ((u >> 16) & 1u);
  return (unsigned short)(r >> 16);
}
__device__ __forceinline__ float b2f(unsigned short s) {
  return __uint_as_float((unsigned)s << 16);
}
__device__ __forceinline__ float bf_lo(unsigned p) { return __uint_as_float(p << 16); }
__device__ __forceinline__ float bf_hi(unsigned p) { return __uint_as_float(p & 0xffff0000u); }

// ---------------- degree (int atomics) ----------------
__global__ void deg_kernel(const int* __restrict__ dst, int* __restrict__ deg) {
  int i = blockIdx.x * blockDim.x + threadIdx.x;
  int n = gridDim.x * blockDim.x;
  for (; i < NE; i += n) atomicAdd(&deg[dst[i]], 1);
}

__global__ void dinv_kernel(const int* __restrict__ deg, float* __restrict__ dinv) {
  int i = blockIdx.x * blockDim.x + threadIdx.x;
  if (i < NN) dinv[i] = rsqrtf((float)deg[i] + 1.0f);
}

// ---------------- W -> bf16 transposed: wt[n][k] = W[k][n] ----------------
__global__ void wprep_kernel(const float* __restrict__ W1, const float* __restrict__ W2,
                             const float* __restrict__ W3, unsigned short* __restrict__ wt1,
                             unsigned short* __restrict__ wt2, unsigned short* __restrict__ wt3) {
  int t = blockIdx.x * blockDim.x + threadIdx.x;
  if (t < 16384) {
    int n = t >> 7, k = t & 127; wt1[t] = f2b(W1[k * 128 + n]);
  } else if (t < 32768) {
    int i = t - 16384; int n = i >> 7, k = i & 127; wt2[i] = f2b(W2[k * 128 + n]);
  } else if (t < 40960) {
    int i = t - 32768; int n = i >> 7, k = i & 127; wt3[i] = f2b(W3[k * 64 + n]);
  }
}

// ---------------- hierarchical exclusive scan: deg -> off ----------------
__global__ __launch_bounds__(1024) void scan_blocks(const int* __restrict__ deg,
                                                    int* __restrict__ off,
                                                    int* __restrict__ bsum) {
  __shared__ int wsum[16];
  const int t = threadIdx.x, lane = t & 63, wv = t >> 6;
  const int i = blockIdx.x * 1024 + t;
  int v = (i < NN) ? deg[i] : 0;
  int sv = v;
  #pragma unroll
  for (int d = 1; d < 64; d <<= 1) {
    int u = __shfl_up(sv, d, 64);
    if (lane >= d) sv += u;
  }
  if (lane == 63) wsum[wv] = sv;
  __syncthreads();
  if (t < 16) {
    int w0 = wsum[t];
    #pragma unroll
    for (int d = 1; d < 16; d <<= 1) {
      int u = __shfl_up(w0, d, 64);
      if (t >= d) w0 += u;
    }
    wsum[t] = w0;
  }
  __syncthreads();
  int excl = (wv ? wsum[wv - 1] : 0) + (sv - v);
  if (i < NN) off[i] = excl;
  if (t == 0) bsum[blockIdx.x] = wsum[15];
}

__global__ __launch_bounds__(128) void scan_bsum(int* __restrict__ bsum) {
  __shared__ int ws0;
  const int t = threadIdx.x, lane = t & 63, wv = t >> 6;
  int v = (t < NB_SCAN) ? bsum[t] : 0;
  int sv = v;
  #pragma unroll
  for (int d = 1; d < 64; d <<= 1) {
    int u = __shfl_up(sv, d, 64);
    if (lane >= d) sv += u;
  }
  if (wv == 0 && lane == 63) ws0 = sv;
  __syncthreads();
  int excl = (wv ? ws0 : 0) + (sv - v);
  if (t < NB_SCAN) bsum[t] = excl;
}

__global__ __launch_bounds__(1024) void scan_add(int* __restrict__ off,
                                                 const int* __restrict__ bsum) {
  int i = blockIdx.x * 1024 + threadIdx.x;
  if (i < NN) off[i] += bsum[blockIdx.x];
  if (i == 0) off[NN] = NE;
}

// ---------------- counting-sort fill: CSR edge list with precomputed coef ----------------
__global__ void fill_kernel(const int* __restrict__ src, const int* __restrict__ dst,
                            const float* __restrict__ dinv, const int* __restrict__ off,
                            int* __restrict__ cursor, int2* __restrict__ einfo) {
  int i = blockIdx.x * blockDim.x + threadIdx.x;
  int n = gridDim.x * blockDim.x;
  for (; i < NE; i += n) {
    int s = src[i], d = dst[i];
    int pos = off[d] + atomicAdd(&cursor[d], 1);
    einfo[pos] = make_int2(s, __float_as_int(dinv[s] * dinv[d]));
  }
}

// ---------------- MFMA GEMM: h[NN][NOUT] bf16 = in[NN][128] @ Wt^T ----------------
// 64 rows/block, 4 waves; wave = 16 rows x NOUT cols; K=128 as 4x mfma_16x16x32_bf16.
// A frags: row=lane&15, k=(lane>>4)*8+j (16B global loads). B from wt[n][k] (L1-resident).
// C/D: col=lane&15, row=(lane>>4)*4+reg (m89-verified). Epilogue transposes via LDS.
template<int NOUT, bool AF32>
__global__ __launch_bounds__(256) void mfma_gemm(
    const void* __restrict__ in_, const unsigned short* __restrict__ wt,
    unsigned short* __restrict__ h)
{
  constexpr int NCT = NOUT / 16;
  __shared__ float es[64 * 132];
  const int t = threadIdx.x;
  const int w = t >> 6;
  const int l = t & 63;
  const int row0 = blockIdx.x * 64;

  int arow = row0 + w * 16 + (l & 15);
  if (arow > NN - 1) arow = NN - 1;
  const int kbase = (l >> 4) * 8;

  short8v a[4];
  if constexpr (AF32) {
    const float* inf = (const float*)in_;
    #pragma unroll
    for (int kt = 0; kt < 4; ++kt) {
      const float* p = inf + (size_t)arow * 128 + kt * 32 + kbase;
      float4 u0 = *(const float4*)p;
      float4 u1 = *(const float4*)(p + 4);
      short8v av;
      av[0] = (short)f2b(u0.x); av[1] = (short)f2b(u0.y);
      av[2] = (short)f2b(u0.z); av[3] = (short)f2b(u0.w);
      av[4] = (short)f2b(u1.x); av[5] = (short)f2b(u1.y);
      av[6] = (short)f2b(u1.z); av[7] = (short)f2b(u1.w);
      a[kt] = av;
    }
  } else {
    const unsigned short* inb = (const unsigned short*)in_;
    #pragma unroll
    for (int kt = 0; kt < 4; ++kt)
      a[kt] = *(const short8v*)(inb + (size_t)arow * 128 + kt * 32 + kbase);
  }

  const int bofs = (l & 15) * 128 + kbase;   // within a 16-col group of wt

  float4v acc[NCT];
  #pragma unroll
  for (int c = 0; c < NCT; ++c) acc[c] = (float4v){0.f, 0.f, 0.f, 0.f};

  #pragma unroll
  for (int kt = 0; kt < 4; ++kt) {
    #pragma unroll
    for (int c = 0; c < NCT; ++c) {
      short8v b = *(const short8v*)(wt + (size_t)c * 16 * 128 + bofs + kt * 32);
      acc[c] = __builtin_amdgcn_mfma_f32_16x16x32_bf16(a[kt], b, acc[c], 0, 0, 0);
    }
  }

  // epilogue: acc -> LDS f32 tile -> packed bf16 coalesced stores
  const int q = l >> 4, c16 = l & 15;
  #pragma unroll
  for (int c = 0; c < NCT; ++c) {
    #pragma unroll
    for (int r = 0; r < 4; ++r)
      es[(w * 16 + q * 4 + r) * 132 + c * 16 + c16] = acc[c][r];
  }
  __syncthreads();
  constexpr int GPR = NOUT / 8;   // 8-col groups per row
  #pragma unroll
  for (int it = 0; it < 64 * GPR / 256; ++it) {
    int f = t + it * 256;
    int r = f / GPR, g = f % GPR;
    int row = row0 + r;
    if (row < NN) {
      const float* p = &es[r * 132 + g * 8];
      uint4 o;
      o.x = (unsigned)f2b(p[0]) | ((unsigned)f2b(p[1]) << 16);
      o.y = (unsigned)f2b(p[2]) | ((unsigned)f2b(p[3]) << 16);
      o.z = (unsigned)f2b(p[4]) | ((unsigned)f2b(p[5]) << 16);
      o.w = (unsigned)f2b(p[6]) | ((unsigned)f2b(p[7]) << 16);
      *(uint4*)(h + (size_t)row * NOUT + g * 8) = o;
    }
  }
}

// ---------------- aggregate: out[d] = b + dinv[d]^2*h[d] + sum_e coef*h[src_e] ----------------
// one wave per dst node; h bf16, f32 accum; 8-wide ILP gather groups.
// BF16RELU: apply ReLU and emit packed bf16 (feeds next MFMA GEMM); else f32 out.
template<int NOUT, bool BF16RELU>
__global__ __launch_bounds__(256) void agg_kernel(
    const unsigned short* __restrict__ h, const int* __restrict__ off,
    const int2* __restrict__ einfo, const float* __restrict__ dinv,
    const float* __restrict__ bias, void* __restrict__ out_)
{
  const int w = (int)((blockIdx.x * 256 + threadIdx.x) >> 6);
  if (w >= NN) return;
  const int lane = threadIdx.x & 63;
  const int n0 = off[w], n1 = off[w + 1];
  const float di = dinv[w];
  const float di2 = di * di;
  if constexpr (NOUT == 128) {
    const unsigned* hu = (const unsigned*)h;
    unsigned pw = hu[(size_t)w * 64 + lane];
    float2 bv = ((const float2*)bias)[lane];
    float a0 = fmaf(bf_lo(pw), di2, bv.x);
    float a1 = fmaf(bf_hi(pw), di2, bv.y);
    for (int e = n0; e < n1; e += 8) {
      int   idx[8];
      float cf[8];
      unsigned q[8];
      #pragma unroll
      for (int k = 0; k < 8; ++k) {
        int ee = e + k;
        bool ok = ee < n1;
        int2 sc = einfo[ok ? ee : n0];
        idx[k] = sc.x;
        cf[k]  = ok ? __int_as_float(sc.y) : 0.f;
      }
      #pragma unroll
      for (int k = 0; k < 8; ++k) q[k] = hu[(size_t)idx[k] * 64 + lane];
      #pragma unroll
      for (int k = 0; k < 8; ++k) {
        a0 = fmaf(bf_lo(q[k]), cf[k], a0);
        a1 = fmaf(bf_hi(q[k]), cf[k], a1);
      }
    }
    if constexpr (BF16RELU) {
      a0 = fmaxf(a0, 0.f); a1 = fmaxf(a1, 0.f);
      unsigned o = (unsigned)f2b(a0) | ((unsigned)f2b(a1) << 16);
      ((unsigned*)out_)[(size_t)w * 64 + lane] = o;
    } else {
      float2 o; o.x = a0; o.y = a1;
      ((float2*)out_)[(size_t)w * 64 + lane] = o;
    }
  } else {
    unsigned short pw = h[(size_t)w * 64 + lane];
    float a0 = fmaf(b2f(pw), di2, bias[lane]);
    for (int e = n0; e < n1; e += 8) {
      int   idx[8];
      float cf[8];
      unsigned short q[8];
      #pragma unroll
      for (int k = 0; k < 8; ++k) {
        int ee = e + k;
        bool ok = ee < n1;
        int2 sc = einfo[ok ? ee : n0];
        idx[k] = sc.x;
        cf[k]  = ok ? __int_as_float(sc.y) : 0.f;
      }
      #pragma unroll
      for (int k = 0; k < 8; ++k) q[k] = h[(size_t)idx[k] * 64 + lane];
      #pragma unroll
      for (int k = 0; k < 8; ++k) a0 = fmaf(b2f(q[k]), cf[k], a0);
    }
    ((float*)out_)[(size_t)w * 64 + lane] = a0;
  }
}

extern "C" void kernel_launch(void* const* d_in, const int* in_sizes, int n_in,
                              void* d_out, int out_size, void* d_ws, size_t ws_size,
                              hipStream_t stream) {
  const float* x  = (const float*)d_in[0];
  const int*   ei = (const int*)d_in[1];
  const float* W1 = (const float*)d_in[2];
  const float* b1 = (const float*)d_in[3];
  const float* W2 = (const float*)d_in[4];
  const float* b2 = (const float*)d_in[5];
  const float* W3 = (const float*)d_in[6];
  const float* b3 = (const float*)d_in[7];
  float* out = (float*)d_out;

  const int* src = ei;
  const int* dst = ei + NE;

  // workspace layout (float elements)
  float* ws = (float*)d_ws;
  int*   deg    = (int*)ws;                         // NN
  float* dinv   = ws + NN;                          // NN
  int*   off    = (int*)(ws + 2 * NN);              // NN+4
  int*   cursor = (int*)(ws + 3 * NN + 4);          // NN
  int*   bsum   = (int*)(ws + 4 * NN + 4);          // 128
  int2*  einfo  = (int2*)(ws + 4 * NN + 132);       // NE int2
  unsigned short* wt1 = (unsigned short*)(ws + 4 * NN + 132 + 2 * NE);  // 16384 bf16
  unsigned short* wt2 = wt1 + 16384;                                     // 16384 bf16
  unsigned short* wt3 = wt2 + 16384;                                     // 8192 bf16
  unsigned short* hA  = (unsigned short*)(ws + 4 * NN + 132 + 2 * NE + 20480); // NN*128 bf16
  unsigned short* hB  = hA + (size_t)NN * 128;                                 // NN*128 bf16

  hipMemsetAsync(deg, 0, NN * sizeof(int), stream);
  hipMemsetAsync(cursor, 0, NN * sizeof(int), stream);
  wprep_kernel<<<160, 256, 0, stream>>>(W1, W2, W3, wt1, wt2, wt3);
  deg_kernel<<<1024, 256, 0, stream>>>(dst, deg);
  dinv_kernel<<<(NN + 255) / 256, 256, 0, stream>>>(deg, dinv);
  scan_blocks<<<NB_SCAN, 1024, 0, stream>>>(deg, off, bsum);
  scan_bsum<<<1, 128, 0, stream>>>(bsum);
  scan_add<<<NB_SCAN, 1024, 0, stream>>>(off, bsum);
  fill_kernel<<<1024, 256, 0, stream>>>(src, dst, dinv, off, cursor, einfo);

  const int AGG_BLOCKS = (NN * 64 + 255) / 256;   // one wave per node
  const int GEMM_BLOCKS = (NN + 63) / 64;

  // layer 1: hA = x@W1 (f32 in); hB = relu(agg(hA)) bf16
  mfma_gemm<128, true><<<GEMM_BLOCKS, 256, 0, stream>>>(x, wt1, hA);
  agg_kernel<128, true><<<AGG_BLOCKS, 256, 0, stream>>>(hA, off, einfo, dinv, b1, hB);
  // layer 2
  mfma_gemm<128, false><<<GEMM_BLOCKS, 256, 0, stream>>>(hB, wt2, hA);
  agg_kernel<128, true><<<AGG_BLOCKS, 256, 0, stream>>>(hA, off, einfo, dinv, b2, hB);
  // layer 3 (64-wide, f32 final out)
  mfma_gemm<64, false><<<GEMM_BLOCKS, 256, 0, stream>>>(hB, wt3, hA);
  agg_kernel<64, false><<<AGG_BLOCKS, 256, 0, stream>>>(hA, off, einfo, dinv, b3, out);
}

// Round 10
// 272.118 us; speedup vs baseline: 3.1751x; 1.0776x over previous
//
#include <hip/hip_runtime.h>

#define NN 100000
#define NE 600000
#define NB_SCAN 98   // 98 * 1024 = 100352 >= NN

typedef __attribute__((ext_vector_type(8))) short short8v;   // 8 bf16 (4 VGPRs)
typedef __attribute__((ext_vector_type(4))) float float4v;   // MFMA acc

// bf16 helpers (RNE; inputs are finite)
__device__ __forceinline__ unsigned short f2b(float f) {
  unsigned u = __float_as_uint(f);
  unsigned r = u + 0x7fffu + ((u >> 16) & 1u);
  return (unsigned short)(r >> 16);
}
__device__ __forceinline__ float b2f(unsigned short s) {
  return __uint_as_float((unsigned)s << 16);
}
__device__ __forceinline__ float bf_lo(unsigned p) { return __uint_as_float(p << 16); }
__device__ __forceinline__ float bf_hi(unsigned p) { return __uint_as_float(p & 0xffff0000u); }

// ---------------- degree (int atomics) ----------------
__global__ void deg_kernel(const int* __restrict__ dst, int* __restrict__ deg) {
  int i = blockIdx.x * blockDim.x + threadIdx.x;
  int n = gridDim.x * blockDim.x;
  for (; i < NE; i += n) atomicAdd(&deg[dst[i]], 1);
}

// ---------------- W -> bf16 transposed: wt[n][k] = W[k][n] ----------------
__global__ void wprep_kernel(const float* __restrict__ W1, const float* __restrict__ W2,
                             const float* __restrict__ W3, unsigned short* __restrict__ wt1,
                             unsigned short* __restrict__ wt2, unsigned short* __restrict__ wt3) {
  int t = blockIdx.x * blockDim.x + threadIdx.x;
  if (t < 16384) {
    int n = t >> 7, k = t & 127; wt1[t] = f2b(W1[k * 128 + n]);
  } else if (t < 32768) {
    int i = t - 16384; int n = i >> 7, k = i & 127; wt2[i] = f2b(W2[k * 128 + n]);
  } else if (t < 40960) {
    int i = t - 32768; int n = i >> 7, k = i & 127; wt3[i] = f2b(W3[k * 64 + n]);
  }
}

// ---------------- hierarchical exclusive scan: deg -> off (+ fused dinv) ----------------
__global__ __launch_bounds__(1024) void scan_blocks(const int* __restrict__ deg,
                                                    int* __restrict__ off,
                                                    int* __restrict__ bsum,
                                                    float* __restrict__ dinv) {
  __shared__ int wsum[16];
  const int t = threadIdx.x, lane = t & 63, wv = t >> 6;
  const int i = blockIdx.x * 1024 + t;
  int v = (i < NN) ? deg[i] : 0;
  if (i < NN) dinv[i] = rsqrtf((float)v + 1.0f);
  int sv = v;
  #pragma unroll
  for (int d = 1; d < 64; d <<= 1) {
    int u = __shfl_up(sv, d, 64);
    if (lane >= d) sv += u;
  }
  if (lane == 63) wsum[wv] = sv;
  __syncthreads();
  if (t < 16) {
    int w0 = wsum[t];
    #pragma unroll
    for (int d = 1; d < 16; d <<= 1) {
      int u = __shfl_up(w0, d, 64);
      if (t >= d) w0 += u;
    }
    wsum[t] = w0;
  }
  __syncthreads();
  int excl = (wv ? wsum[wv - 1] : 0) + (sv - v);
  if (i < NN) off[i] = excl;
  if (t == 0) bsum[blockIdx.x] = wsum[15];
}

__global__ __launch_bounds__(128) void scan_bsum(int* __restrict__ bsum) {
  __shared__ int ws0;
  const int t = threadIdx.x, lane = t & 63, wv = t >> 6;
  int v = (t < NB_SCAN) ? bsum[t] : 0;
  int sv = v;
  #pragma unroll
  for (int d = 1; d < 64; d <<= 1) {
    int u = __shfl_up(sv, d, 64);
    if (lane >= d) sv += u;
  }
  if (wv == 0 && lane == 63) ws0 = sv;
  __syncthreads();
  int excl = (wv ? ws0 : 0) + (sv - v);
  if (t < NB_SCAN) bsum[t] = excl;
}

__global__ __launch_bounds__(1024) void scan_add(int* __restrict__ off,
                                                 const int* __restrict__ bsum) {
  int i = blockIdx.x * 1024 + threadIdx.x;
  if (i < NN) off[i] += bsum[blockIdx.x];
  if (i == 0) off[NN] = NE;
}

// ---------------- counting-sort fill: CSR edge list with precomputed coef ----------------
__global__ void fill_kernel(const int* __restrict__ src, const int* __restrict__ dst,
                            const float* __restrict__ dinv, const int* __restrict__ off,
                            int* __restrict__ cursor, int2* __restrict__ einfo) {
  int i = blockIdx.x * blockDim.x + threadIdx.x;
  int n = gridDim.x * blockDim.x;
  for (; i < NE; i += n) {
    int s = src[i], d = dst[i];
    int pos = off[d] + atomicAdd(&cursor[d], 1);
    einfo[pos] = make_int2(s, __float_as_int(dinv[s] * dinv[d]));
  }
}

// ---------------- MFMA GEMM: h[NN][NOUT] bf16 = in[NN][128] @ Wt^T ----------------
template<int NOUT, bool AF32>
__global__ __launch_bounds__(256) void mfma_gemm(
    const void* __restrict__ in_, const unsigned short* __restrict__ wt,
    unsigned short* __restrict__ h)
{
  constexpr int NCT = NOUT / 16;
  __shared__ float es[64 * 132];
  const int t = threadIdx.x;
  const int w = t >> 6;
  const int l = t & 63;
  const int row0 = blockIdx.x * 64;

  int arow = row0 + w * 16 + (l & 15);
  if (arow > NN - 1) arow = NN - 1;
  const int kbase = (l >> 4) * 8;

  short8v a[4];
  if constexpr (AF32) {
    const float* inf = (const float*)in_;
    #pragma unroll
    for (int kt = 0; kt < 4; ++kt) {
      const float* p = inf + (size_t)arow * 128 + kt * 32 + kbase;
      float4 u0 = *(const float4*)p;
      float4 u1 = *(const float4*)(p + 4);
      short8v av;
      av[0] = (short)f2b(u0.x); av[1] = (short)f2b(u0.y);
      av[2] = (short)f2b(u0.z); av[3] = (short)f2b(u0.w);
      av[4] = (short)f2b(u1.x); av[5] = (short)f2b(u1.y);
      av[6] = (short)f2b(u1.z); av[7] = (short)f2b(u1.w);
      a[kt] = av;
    }
  } else {
    const unsigned short* inb = (const unsigned short*)in_;
    #pragma unroll
    for (int kt = 0; kt < 4; ++kt)
      a[kt] = *(const short8v*)(inb + (size_t)arow * 128 + kt * 32 + kbase);
  }

  const int bofs = (l & 15) * 128 + kbase;

  float4v acc[NCT];
  #pragma unroll
  for (int c = 0; c < NCT; ++c) acc[c] = (float4v){0.f, 0.f, 0.f, 0.f};

  #pragma unroll
  for (int kt = 0; kt < 4; ++kt) {
    #pragma unroll
    for (int c = 0; c < NCT; ++c) {
      short8v b = *(const short8v*)(wt + (size_t)c * 16 * 128 + bofs + kt * 32);
      acc[c] = __builtin_amdgcn_mfma_f32_16x16x32_bf16(a[kt], b, acc[c], 0, 0, 0);
    }
  }

  const int q = l >> 4, c16 = l & 15;
  #pragma unroll
  for (int c = 0; c < NCT; ++c) {
    #pragma unroll
    for (int r = 0; r < 4; ++r)
      es[(w * 16 + q * 4 + r) * 132 + c * 16 + c16] = acc[c][r];
  }
  __syncthreads();
  constexpr int GPR = NOUT / 8;
  #pragma unroll
  for (int it = 0; it < 64 * GPR / 256; ++it) {
    int f = t + it * 256;
    int r = f / GPR, g = f % GPR;
    int row = row0 + r;
    if (row < NN) {
      const float* p = &es[r * 132 + g * 8];
      uint4 o;
      o.x = (unsigned)f2b(p[0]) | ((unsigned)f2b(p[1]) << 16);
      o.y = (unsigned)f2b(p[2]) | ((unsigned)f2b(p[3]) << 16);
      o.z = (unsigned)f2b(p[4]) | ((unsigned)f2b(p[5]) << 16);
      o.w = (unsigned)f2b(p[6]) | ((unsigned)f2b(p[7]) << 16);
      *(uint4*)(h + (size_t)row * NOUT + g * 8) = o;
    }
  }
}

// ---------------- aggregate (quad-edge): out[d] = b + dinv^2*h[d] + sum coef*h[src] ----------------
// wave per dst node, split into GS edge-slot groups of LPR lanes; each gather
// instruction fetches GS distinct rows (uint4 = 8 cols per lane). 2-deep ILP.
// Cross-group shfl_xor reduce at the end. Loop only entered when deg>=1, so
// the einfo[n0] clamp is always in-bounds.
template<int NOUT, bool BF16RELU>
__global__ __launch_bounds__(256) void agg_kernel(
    const unsigned short* __restrict__ h, const int* __restrict__ off,
    const int2* __restrict__ einfo, const float* __restrict__ dinv,
    const float* __restrict__ bias, void* __restrict__ out_)
{
  constexpr int LPR = NOUT / 8;     // lanes per row (uint4 granularity): 16 or 8
  constexpr int GS  = 64 / LPR;     // edge slots per wave: 4 or 8
  const int w = (int)((blockIdx.x * 256 + threadIdx.x) >> 6);
  if (w >= NN) return;
  const int lane = threadIdx.x & 63;
  const int g = lane / LPR;
  const int c = lane % LPR;
  const int n0 = off[w], n1 = off[w + 1];
  const uint4* hu4 = (const uint4*)h;

  float acc[8];
  if (g == 0) {
    const float di = dinv[w];
    const float di2 = di * di;
    uint4 sv = hu4[(size_t)w * LPR + c];
    const float4* b4 = (const float4*)bias;
    float4 bl = b4[c * 2], bh = b4[c * 2 + 1];
    acc[0] = fmaf(bf_lo(sv.x), di2, bl.x);
    acc[1] = fmaf(bf_hi(sv.x), di2, bl.y);
    acc[2] = fmaf(bf_lo(sv.y), di2, bl.z);
    acc[3] = fmaf(bf_hi(sv.y), di2, bl.w);
    acc[4] = fmaf(bf_lo(sv.z), di2, bh.x);
    acc[5] = fmaf(bf_hi(sv.z), di2, bh.y);
    acc[6] = fmaf(bf_lo(sv.w), di2, bh.z);
    acc[7] = fmaf(bf_hi(sv.w), di2, bh.w);
  } else {
    #pragma unroll
    for (int j = 0; j < 8; ++j) acc[j] = 0.f;
  }

  for (int e = n0; e < n1; e += 2 * GS) {
    int e0 = e + g, e1 = e + GS + g;
    bool ok0 = e0 < n1, ok1 = e1 < n1;
    int2 s0 = einfo[ok0 ? e0 : n0];
    int2 s1 = einfo[ok1 ? e1 : n0];
    float c0 = ok0 ? __int_as_float(s0.y) : 0.f;
    float c1 = ok1 ? __int_as_float(s1.y) : 0.f;
    uint4 v0 = hu4[(size_t)s0.x * LPR + c];
    uint4 v1 = hu4[(size_t)s1.x * LPR + c];
    acc[0] = fmaf(bf_lo(v0.x), c0, acc[0]);
    acc[1] = fmaf(bf_hi(v0.x), c0, acc[1]);
    acc[2] = fmaf(bf_lo(v0.y), c0, acc[2]);
    acc[3] = fmaf(bf_hi(v0.y), c0, acc[3]);
    acc[4] = fmaf(bf_lo(v0.z), c0, acc[4]);
    acc[5] = fmaf(bf_hi(v0.z), c0, acc[5]);
    acc[6] = fmaf(bf_lo(v0.w), c0, acc[6]);
    acc[7] = fmaf(bf_hi(v0.w), c0, acc[7]);
    acc[0] = fmaf(bf_lo(v1.x), c1, acc[0]);
    acc[1] = fmaf(bf_hi(v1.x), c1, acc[1]);
    acc[2] = fmaf(bf_lo(v1.y), c1, acc[2]);
    acc[3] = fmaf(bf_hi(v1.y), c1, acc[3]);
    acc[4] = fmaf(bf_lo(v1.z), c1, acc[4]);
    acc[5] = fmaf(bf_hi(v1.z), c1, acc[5]);
    acc[6] = fmaf(bf_lo(v1.w), c1, acc[6]);
    acc[7] = fmaf(bf_hi(v1.w), c1, acc[7]);
  }

  #pragma unroll
  for (int j = 0; j < 8; ++j) {
    #pragma unroll
    for (int m = LPR; m < 64; m <<= 1)
      acc[j] += __shfl_xor(acc[j], m, 64);
  }

  if (g == 0) {
    if constexpr (BF16RELU) {
      uint4 o;
      o.x = (unsigned)f2b(fmaxf(acc[0], 0.f)) | ((unsigned)f2b(fmaxf(acc[1], 0.f)) << 16);
      o.y = (unsigned)f2b(fmaxf(acc[2], 0.f)) | ((unsigned)f2b(fmaxf(acc[3], 0.f)) << 16);
      o.z = (unsigned)f2b(fmaxf(acc[4], 0.f)) | ((unsigned)f2b(fmaxf(acc[5], 0.f)) << 16);
      o.w = (unsigned)f2b(fmaxf(acc[6], 0.f)) | ((unsigned)f2b(fmaxf(acc[7], 0.f)) << 16);
      ((uint4*)out_)[(size_t)w * LPR + c] = o;
    } else {
      float4 o0, o1;
      o0.x = acc[0]; o0.y = acc[1]; o0.z = acc[2]; o0.w = acc[3];
      o1.x = acc[4]; o1.y = acc[5]; o1.z = acc[6]; o1.w = acc[7];
      ((float4*)out_)[(size_t)w * LPR * 2 + c * 2]     = o0;
      ((float4*)out_)[(size_t)w * LPR * 2 + c * 2 + 1] = o1;
    }
  }
}

extern "C" void kernel_launch(void* const* d_in, const int* in_sizes, int n_in,
                              void* d_out, int out_size, void* d_ws, size_t ws_size,
                              hipStream_t stream) {
  const float* x  = (const float*)d_in[0];
  const int*   ei = (const int*)d_in[1];
  const float* W1 = (const float*)d_in[2];
  const float* b1 = (const float*)d_in[3];
  const float* W2 = (const float*)d_in[4];
  const float* b2 = (const float*)d_in[5];
  const float* W3 = (const float*)d_in[6];
  const float* b3 = (const float*)d_in[7];
  float* out = (float*)d_out;

  const int* src = ei;
  const int* dst = ei + NE;

  // workspace layout (float elements)
  float* ws = (float*)d_ws;
  int*   deg    = (int*)ws;                         // NN
  float* dinv   = ws + NN;                          // NN
  int*   off    = (int*)(ws + 2 * NN);              // NN+4
  int*   cursor = (int*)(ws + 3 * NN + 4);          // NN
  int*   bsum   = (int*)(ws + 4 * NN + 4);          // 128
  int2*  einfo  = (int2*)(ws + 4 * NN + 132);       // NE int2
  unsigned short* wt1 = (unsigned short*)(ws + 4 * NN + 132 + 2 * NE);  // 16384 bf16
  unsigned short* wt2 = wt1 + 16384;
  unsigned short* wt3 = wt2 + 16384;
  unsigned short* hA  = (unsigned short*)(ws + 4 * NN + 132 + 2 * NE + 20480); // NN*128 bf16
  unsigned short* hB  = hA + (size_t)NN * 128;                                 // NN*128 bf16

  hipMemsetAsync(deg, 0, NN * sizeof(int), stream);
  hipMemsetAsync(cursor, 0, NN * sizeof(int), stream);
  wprep_kernel<<<160, 256, 0, stream>>>(W1, W2, W3, wt1, wt2, wt3);
  deg_kernel<<<1024, 256, 0, stream>>>(dst, deg);
  scan_blocks<<<NB_SCAN, 1024, 0, stream>>>(deg, off, bsum, dinv);
  scan_bsum<<<1, 128, 0, stream>>>(bsum);
  scan_add<<<NB_SCAN, 1024, 0, stream>>>(off, bsum);
  fill_kernel<<<1024, 256, 0, stream>>>(src, dst, dinv, off, cursor, einfo);

  const int AGG_BLOCKS = (NN * 64 + 255) / 256;   // one wave per node
  const int GEMM_BLOCKS = (NN + 63) / 64;

  // layer 1
  mfma_gemm<128, true><<<GEMM_BLOCKS, 256, 0, stream>>>(x, wt1, hA);
  agg_kernel<128, true><<<AGG_BLOCKS, 256, 0, stream>>>(hA, off, einfo, dinv, b1, hB);
  // layer 2
  mfma_gemm<128, false><<<GEMM_BLOCKS, 256, 0, stream>>>(hB, wt2, hA);
  agg_kernel<128, true><<<AGG_BLOCKS, 256, 0, stream>>>(hA, off, einfo, dinv, b2, hB);
  // layer 3 (64-wide, f32 final out)
  mfma_gemm<64, false><<<GEMM_BLOCKS, 256, 0, stream>>>(hB, wt3, hA);
  agg_kernel<64, false><<<AGG_BLOCKS, 256, 0, stream>>>(hA, off, einfo, dinv, b3, out);
}